// Round 3
// baseline (369.500 us; speedup 1.0000x reference)
//
#include <hip/hip_runtime.h>
#include <hip/hip_bf16.h>

typedef __hip_bfloat16 bf16;

__device__ __forceinline__ float b2f(bf16 x) { return __bfloat162float(x); }

// Inputs are float32 (proved by R1's NaN signature); detector kept as cheap
// insurance in case the harness ever feeds bf16. Outputs are float32 (proved
// by R2's 4.195 > 3.70 bf16-error bound).
template<bool F32>
__device__ __forceinline__ float ld(const void* p, size_t i) {
  if constexpr (F32) return ((const float*)p)[i];
  else return b2f(((const bf16*)p)[i]);
}

template<bool F32>
__device__ __forceinline__ void ld8(const void* p, size_t i, float v[8]) {
  if constexpr (F32) {
    const float4 a = *(const float4*)((const float*)p + i);
    const float4 b = *(const float4*)((const float*)p + i + 4);
    v[0]=a.x; v[1]=a.y; v[2]=a.z; v[3]=a.w;
    v[4]=b.x; v[5]=b.y; v[6]=b.z; v[7]=b.w;
  } else {
    union { uint4 u; bf16 h[8]; } t;
    t.u = *(const uint4*)((const bf16*)p + i);
    #pragma unroll
    for (int c = 0; c < 8; ++c) v[c] = b2f(t.h[c]);
  }
}

// B=16, N=128, D=64 ; nodes = B*N = 2048
// ws layout (floats):
//   q @0 (131072) | k @131072 | pred @262144 | err @393216 | pl @524288
//   mag @655360 (16) | stats @655376 (2) | flag @655378 (1 int)

// ---------------- Kernel 0: input dtype detect -------------------------------
__global__ void k0_detect(const void* __restrict__ state, int* __restrict__ flag) {
  const int tid = threadIdx.x;
  bool huge = false;
  for (int i = tid; i < 1024; i += 64) {
    const float x = b2f(((const bf16*)state)[i]);
    if (!(fabsf(x) < 1e5f)) huge = true;   // catches NaN too
  }
  const unsigned long long m = __ballot(huge);
  if (tid == 0) *flag = (m != 0ull) ? 1 : 0;   // 1 => inputs are float32
}

// ---------------- Kernel 1: q, k, raw_pred matvecs + prediction + state_mag --
template<bool F32>
__device__ __forceinline__ void k1_body(
    const void* state, const void* W1, const void* W2, const void* W3,
    float* qw, float* kw, float* pw, float* mag, float* out_pred,
    float* s_state, float (*s_part)[4][64])
{
  const int node = blockIdx.x;
  const int b = node >> 7;
  const int g = threadIdx.x >> 6;   // 4 groups split over j
  const int k = threadIdx.x & 63;   // output column
  if (threadIdx.x < 64) s_state[threadIdx.x] = ld<F32>(state, (size_t)node*64 + threadIdx.x);
  __syncthreads();
  const size_t nb = (size_t)node * 4096;
  float aq = 0.f, ak = 0.f, ap = 0.f;
  #pragma unroll 4
  for (int jj = 0; jj < 16; ++jj) {
    const int j = g*16 + jj;
    const float sj = s_state[j];
    const size_t off = nb + (size_t)j*64 + k;
    aq += sj * ld<F32>(W3, off);   // q = state . W3
    ak += sj * ld<F32>(W2, off);   // k = state . W2
    ap += sj * ld<F32>(W1, off);   // raw_pred = state . W1
  }
  s_part[0][g][k] = aq; s_part[1][g][k] = ak; s_part[2][g][k] = ap;
  __syncthreads();
  if (g == 0) {
    const float qv = s_part[0][0][k] + s_part[0][1][k] + s_part[0][2][k] + s_part[0][3][k];
    const float kv = s_part[1][0][k] + s_part[1][1][k] + s_part[1][2][k] + s_part[1][3][k];
    const float rp = s_part[2][0][k] + s_part[2][1][k] + s_part[2][2][k] + s_part[2][3][k];
    qw[(size_t)node*64 + k] = qv;
    kw[(size_t)node*64 + k] = kv;
    const float raw  = rp - tanhf(rp) * 0.6f;               // UNTANH
    const float pred = tanhf(raw) * 1.8477590650225735f;    // sqrt(2+sqrt(2))
    pw[(size_t)node*64 + k] = pred;
    out_pred[(size_t)node*64 + k] = pred;
  } else if (g == 1) {
    float a = fabsf(s_state[k]);
    #pragma unroll
    for (int s = 32; s; s >>= 1) a += __shfl_xor(a, s, 64);
    if (k == 0) atomicAdd(&mag[b], a);
  }
}

__global__ __launch_bounds__(256) void k1_qkpred(
    const int* __restrict__ flag,
    const void* __restrict__ state,
    const void* __restrict__ W1, const void* __restrict__ W2,
    const void* __restrict__ W3,
    float* __restrict__ qw, float* __restrict__ kw, float* __restrict__ pw,
    float* __restrict__ mag, float* __restrict__ out_pred)
{
  __shared__ float s_state[64];
  __shared__ float s_part[3][4][64];
  if (*flag) k1_body<true >(state, W1, W2, W3, qw, kw, pw, mag, out_pred, s_state, s_part);
  else       k1_body<false>(state, W1, W2, W3, qw, kw, pw, mag, out_pred, s_state, s_part);
}

// ---------------- Kernel 2: attention row, A_new, target, err, plasticity ----
template<bool F32>
__device__ __forceinline__ void k2_body(
    const float* qw, const float* kw, const float* pw,
    const void* noiseA, const void* Aold, const void* outp_in,
    const void* eye, const void* stomach, const void* Ebase,
    float* errw, float* plw, float* stats,
    float* out_target, float* out_A,
    float* s_q, float* s_red, float* s_A)
{
  const int node = blockIdx.x;
  const int b = node >> 7, n = node & 127;
  const int m = threadIdx.x;
  if (m < 64) s_q[m] = qw[(size_t)node*64 + m];
  __syncthreads();
  // raw_A[n,m] = (q[n].k[m]) / 8 + 1e-5*noise_A
  const float4* k4 = (const float4*)(kw + ((size_t)(b*128 + m)) * 64);
  float dot = 0.f;
  #pragma unroll
  for (int i = 0; i < 16; ++i) {
    const float4 v = k4[i];
    dot += s_q[4*i]*v.x + s_q[4*i+1]*v.y + s_q[4*i+2]*v.z + s_q[4*i+3]*v.w;
  }
  const float raw = dot * 0.125f + 1e-5f * ld<F32>(noiseA, (size_t)node*128 + m);
  s_red[m] = raw; __syncthreads();
  for (int s = 64; s >= 1; s >>= 1) { if (m < s) s_red[m] = fmaxf(s_red[m], s_red[m+s]); __syncthreads(); }
  const float rmax = s_red[0]; __syncthreads();
  const float e = expf(raw - rmax);
  s_red[m] = e; __syncthreads();
  for (int s = 64; s >= 1; s >>= 1) { if (m < s) s_red[m] += s_red[m+s]; __syncthreads(); }
  const float S = s_red[0]; __syncthreads();
  const float Pd = e / S;
  const bool keep = (Pd > 0.007751937984496124f) || (raw == rmax);  // 1/(N+1)
  const float ek = keep ? e : 0.f;
  s_red[m] = ek; __syncthreads();
  for (int s = 64; s >= 1; s >>= 1) { if (m < s) s_red[m] += s_red[m+s]; __syncthreads(); }
  const float Sk = s_red[0];
  const float P = ek / Sk;
  const float An = (n < 2) ? 0.f
                 : 0.99f * ld<F32>(Aold, (size_t)node*128 + m) + 0.01f * P;
  s_A[m] = An;
  out_A[(size_t)node*128 + m] = An;
  __syncthreads();
  if (m < 64) {
    float t;
    if (n == 0)      t = ld<F32>(eye, b*64 + m);
    else if (n == 1) t = ld<F32>(stomach, b*64 + m);
    else {
      t = 0.f;
      for (int mm = 0; mm < 128; ++mm)
        t += s_A[mm] * ld<F32>(outp_in, ((size_t)b*128 + mm)*64 + m);
    }
    out_target[(size_t)node*64 + m] = t;
    const float er = pw[(size_t)node*64 + m] - t;
    errw[(size_t)node*64 + m] = er;
    float mx = er;
    #pragma unroll
    for (int s = 32; s; s >>= 1) mx = fmaxf(mx, __shfl_xor(mx, s, 64));
    const float ee = expf(er - mx);
    float ssum = ee;
    #pragma unroll
    for (int s = 32; s; s >>= 1) ssum += __shfl_xor(ssum, s, 64);
    const float Ec = ee / ssum;
    const float Ebl = ld<F32>(Ebase, (size_t)node*64 + m);
    const float Eb0 = (Ebl == 0.f) ? Ec : Ebl;        // bmask logic
    const float Eb  = Eb0 * 0.95f + 0.05f * Ec;       // EMA_SPEED
    const float adv = Ec - Eb;                        // REW_SENS=1
    const float R = -adv * rsqrtf(adv*adv + 1e-6f);   // rms_norm over size-1 axis
    const float maskv = (Eb > 0.f) ? 1.f : 0.f;
    plw[(size_t)node*64 + m] = (1.f - R) * maskv;     // plasticity*mask
    float se = er, se2 = er*er;
    #pragma unroll
    for (int s = 32; s; s >>= 1) { se += __shfl_xor(se, s, 64); se2 += __shfl_xor(se2, s, 64); }
    if (m == 0) { atomicAdd(&stats[0], se); atomicAdd(&stats[1], se2); }
  }
}

__global__ __launch_bounds__(128) void k2_attn(
    const int* __restrict__ flag,
    const float* __restrict__ qw, const float* __restrict__ kw,
    const float* __restrict__ pw,
    const void* __restrict__ noiseA, const void* __restrict__ Aold,
    const void* __restrict__ outp_in,
    const void* __restrict__ eye, const void* __restrict__ stomach,
    const void* __restrict__ Ebase,
    float* __restrict__ errw, float* __restrict__ plw,
    float* __restrict__ stats,
    float* __restrict__ out_target, float* __restrict__ out_A)
{
  __shared__ float s_q[64];
  __shared__ float s_red[128];
  __shared__ float s_A[128];
  if (*flag) k2_body<true >(qw,kw,pw,noiseA,Aold,outp_in,eye,stomach,Ebase,errw,plw,stats,out_target,out_A,s_q,s_red,s_A);
  else       k2_body<false>(qw,kw,pw,noiseA,Aold,outp_in,eye,stomach,Ebase,errw,plw,stats,out_target,out_A,s_q,s_red,s_A);
}

// ---------------- Kernel 3: grads, momentum, W update + row rms-norm ---------
template<bool F32>
__device__ __forceinline__ void k3_body(
    const float* errw, const float* plw,
    const void* state, const void* n1raw, const void* n2raw,
    const float* mag, const float* stats, const int* stepc,
    const void* W1, const void* W2, const void* W3,
    const void* M1, const void* M2, const void* M3,
    float* oW1, float* oW2, float* oW3,
    float* s_err, float* s_ns, float* s_pe, float* s_c, float* s_g)
{
  const int node = blockIdx.x;
  const int b = node >> 7;
  const int tid = threadIdx.x;
  if (tid < 64) {
    s_err[tid] = errw[(size_t)node*64 + tid];
  } else if (tid < 128) {
    const int i = tid - 64;
    const float S1 = stats[0], S2 = stats[1];
    const float Mn = 131072.f;                          // B*N*D
    const float var = (S2 - S1*S1/Mn) / (Mn - 1.f);     // ddof=1
    const float stdv = sqrtf(fmaxf(var, 0.f));
    const float st = ld<F32>(state, (size_t)node*64 + i);
    s_ns[i] = st + ld<F32>(n1raw, (size_t)node*64 + i) / (1.f + mag[b])
                 + ld<F32>(n2raw, (size_t)node*64 + i) * stdv * 0.8f;  // NOISE_SCALE
  }
  __syncthreads();
  if (tid < 64) {
    float e2 = s_err[tid]*s_err[tid];
    float n2 = s_ns[tid]*s_ns[tid];
    #pragma unroll
    for (int s = 32; s; s >>= 1) { e2 += __shfl_xor(e2, s, 64); n2 += __shfl_xor(n2, s, 64); }
    // rms_norm(lg) factorizes: mean(lg^2) = (sum err^2)(sum ns^2)/4096
    const float f = rsqrtf(e2 * n2 * (1.f/4096.f) + 1e-6f);
    s_c[tid] = -s_ns[tid] * f;                          // c_j
    const float sc = (float)stepc[0] + 1.f;
    const float center = fmodf(sc * 0.5f, 64.f);        // SPEED
    float diff = fabsf((float)tid - center);
    diff = fminf(diff, 64.f - diff);
    s_g[tid] = expf(-diff*diff * (1.f/0.020001f));      // 2*WIDTH^2+1e-6
    s_pe[tid] = plw[(size_t)node*64 + tid] * s_err[tid];// pe_i
  }
  __syncthreads();
  const size_t nb = (size_t)node * 4096;
  const int lane8 = tid & 7;
  #pragma unroll
  for (int pass = 0; pass < 2; ++pass) {
    const int r = (tid >> 3) + pass*32;
    const size_t off = nb + (size_t)r*64 + lane8*8;
    float w1v[8], w2v[8], w3v[8], m1v[8], m2v[8], m3v[8];
    ld8<F32>(W1, off, w1v); ld8<F32>(W2, off, w2v); ld8<F32>(W3, off, w3v);
    ld8<F32>(M1, off, m1v); ld8<F32>(M2, off, m2v); ld8<F32>(M3, off, m3v);
    const float pe = s_pe[r];
    float t1[8], t2[8], t3[8];
    float ss1 = 0.f, ss2 = 0.f, ss3 = 0.f;
    #pragma unroll
    for (int c = 0; c < 8; ++c) {
      const int j = lane8*8 + c;
      const float lgterm = pe * s_c[j];                 // p_i * lg_ij
      const float g = s_g[j];
      const float g1 = lgterm + 0.01f*w3v[c] - 0.01f*w1v[c];  // LAT_DECAY, WD
      const float g2 = lgterm + 0.01f*w1v[c] - 0.01f*w2v[c];
      const float g3 = lgterm + 0.01f*w2v[c] - 0.01f*w3v[c];
      const float v1 = w1v[c] + 0.0033f*(0.4f*m1v[c] + 0.6f*g1*g); // LR, MOMENTUM
      const float v2 = w2v[c] + 0.0033f*(0.4f*m2v[c] + 0.6f*g2*g);
      const float v3 = w3v[c] + 0.0033f*(0.4f*m3v[c] + 0.6f*g3*g);
      t1[c] = v1; t2[c] = v2; t3[c] = v3;
      ss1 += v1*v1; ss2 += v2*v2; ss3 += v3*v3;
    }
    #pragma unroll
    for (int s = 1; s <= 4; s <<= 1) {
      ss1 += __shfl_xor(ss1, s, 64);
      ss2 += __shfl_xor(ss2, s, 64);
      ss3 += __shfl_xor(ss3, s, 64);
    }
    const float r1 = rsqrtf(ss1*(1.f/64.f) + 1e-6f);    // row rms over j
    const float r2 = rsqrtf(ss2*(1.f/64.f) + 1e-6f);
    const float r3 = rsqrtf(ss3*(1.f/64.f) + 1e-6f);
    float4 a, bb;
    a = make_float4(t1[0]*r1, t1[1]*r1, t1[2]*r1, t1[3]*r1);
    bb = make_float4(t1[4]*r1, t1[5]*r1, t1[6]*r1, t1[7]*r1);
    *(float4*)(oW1 + off) = a; *(float4*)(oW1 + off + 4) = bb;
    a = make_float4(t2[0]*r2, t2[1]*r2, t2[2]*r2, t2[3]*r2);
    bb = make_float4(t2[4]*r2, t2[5]*r2, t2[6]*r2, t2[7]*r2);
    *(float4*)(oW2 + off) = a; *(float4*)(oW2 + off + 4) = bb;
    a = make_float4(t3[0]*r3, t3[1]*r3, t3[2]*r3, t3[3]*r3);
    bb = make_float4(t3[4]*r3, t3[5]*r3, t3[6]*r3, t3[7]*r3);
    *(float4*)(oW3 + off) = a; *(float4*)(oW3 + off + 4) = bb;
  }
}

__global__ __launch_bounds__(256) void k3_update(
    const int* __restrict__ flag,
    const float* __restrict__ errw, const float* __restrict__ plw,
    const void* __restrict__ state, const void* __restrict__ n1raw,
    const void* __restrict__ n2raw,
    const float* __restrict__ mag, const float* __restrict__ stats,
    const int* __restrict__ stepc,
    const void* __restrict__ W1, const void* __restrict__ W2,
    const void* __restrict__ W3,
    const void* __restrict__ M1, const void* __restrict__ M2,
    const void* __restrict__ M3,
    float* __restrict__ oW1, float* __restrict__ oW2, float* __restrict__ oW3)
{
  __shared__ float s_err[64], s_ns[64], s_pe[64], s_c[64], s_g[64];
  if (*flag) k3_body<true >(errw,plw,state,n1raw,n2raw,mag,stats,stepc,W1,W2,W3,M1,M2,M3,oW1,oW2,oW3,s_err,s_ns,s_pe,s_c,s_g);
  else       k3_body<false>(errw,plw,state,n1raw,n2raw,mag,stats,stepc,W1,W2,W3,M1,M2,M3,oW1,oW2,oW3,s_err,s_ns,s_pe,s_c,s_g);
}

extern "C" void kernel_launch(void* const* d_in, const int* in_sizes, int n_in,
                              void* d_out, int out_size, void* d_ws, size_t ws_size,
                              hipStream_t stream) {
  const void* eye     = d_in[0];
  const void* stomach = d_in[1];
  const void* state   = d_in[2];
  const void* outp    = d_in[3];
  const void* W1      = d_in[4];
  const void* W2      = d_in[5];
  const void* W3      = d_in[6];
  const void* M1      = d_in[7];
  const void* M2      = d_in[8];
  const void* M3      = d_in[9];
  const void* Ebase   = d_in[10];
  const void* Aold    = d_in[11];
  const void* noiseA  = d_in[12];
  const void* n1raw   = d_in[13];
  const void* n2raw   = d_in[14];
  const int*  stepc   = (const int*)d_in[15];

  float* ws    = (float*)d_ws;
  float* qw    = ws;
  float* kw    = ws + 131072;
  float* pw    = ws + 262144;
  float* errw  = ws + 393216;
  float* plw   = ws + 524288;
  float* mag   = ws + 655360;
  float* stats = ws + 655376;
  int*   flag  = (int*)(ws + 655378);

  float* out        = (float*)d_out;
  float* out_pred   = out;                 // (B,N,D)
  float* out_target = out + 131072;        // (B,N,D)
  float* out_A      = out + 262144;        // (B,N,N)
  float* oW1        = out + 524288;        // (B,N,D,D)
  float* oW2        = out + 8912896;
  float* oW3        = out + 17301504;

  hipMemsetAsync(mag, 0, 18 * sizeof(float), stream);
  k0_detect<<<1, 64, 0, stream>>>(state, flag);
  k1_qkpred<<<2048, 256, 0, stream>>>(flag, state, W1, W2, W3, qw, kw, pw, mag, out_pred);
  k2_attn<<<2048, 128, 0, stream>>>(flag, qw, kw, pw, noiseA, Aold, outp, eye, stomach,
                                    Ebase, errw, plw, stats, out_target, out_A);
  k3_update<<<2048, 256, 0, stream>>>(flag, errw, plw, state, n1raw, n2raw, mag, stats,
                                      stepc, W1, W2, W3, M1, M2, M3, oW1, oW2, oW3);
}